// Round 11
// baseline (171.657 us; speedup 1.0000x reference)
//
#include <hip/hip_runtime.h>
#include <hip/hip_bf16.h>
#include <stdint.h>

// MHA forward: B=4, S=2048, D=1024, H=16, dk=64. fp32 in/out, bf16 MFMA internally.
// Pipeline: cast -> QKV GEMM (bf16, BK=64 swizzled LDS, V written transposed in epilogue)
//           -> causal flash attention (dual-q per wave, static-max softmax, KVBLK=128
//              double-buffered: one barrier per 128 kv rows) -> out GEMM.

typedef unsigned short u16;
typedef short bf16x8 __attribute__((ext_vector_type(8)));
typedef float f32x4 __attribute__((ext_vector_type(4)));
typedef unsigned short u16x8 __attribute__((ext_vector_type(8)));

#define S_LEN 2048
#define DMODEL 1024
#define NH 16

__device__ __forceinline__ u16 f2bf(float f) {
    unsigned u = __builtin_bit_cast(unsigned, f);
    unsigned r = (u + 0x7fffu + ((u >> 16) & 1u)) >> 16;
    return (u16)r;
}

__device__ __forceinline__ float fast_exp2(float x) {
    return __builtin_amdgcn_exp2f(x);
}

__device__ __forceinline__ unsigned cvtpk_bf16(float lo, float hi_) {
    unsigned r;
    asm("v_cvt_pk_bf16_f32 %0, %1, %2" : "=v"(r) : "v"(lo), "v"(hi_));
    return r;
}

__device__ __forceinline__ void gll16(const void* g, void* s) {
    __builtin_amdgcn_global_load_lds((const __attribute__((address_space(1))) unsigned*)g,
                                     (__attribute__((address_space(3))) unsigned*)s, 16, 0, 0);
}

// ---------------- cast: fp32 -> bf16, concat QKV weights ----------------
__global__ __launch_bounds__(256) void cast_all(
    const float* __restrict__ x, const float* __restrict__ wq, const float* __restrict__ wk,
    const float* __restrict__ wv, const float* __restrict__ wo,
    u16* __restrict__ xb, u16* __restrict__ wqkv, u16* __restrict__ wob, int nx) {
    const int NW = DMODEL * DMODEL;
    int i4 = (blockIdx.x * 256 + threadIdx.x) * 4;
    const float* src; u16* dst; int off;
    if (i4 < nx)             { src = x;  dst = xb;            off = i4; }
    else if (i4 < nx + NW)   { src = wq; dst = wqkv;          off = i4 - nx; }
    else if (i4 < nx + 2*NW) { src = wk; dst = wqkv + NW;     off = i4 - nx - NW; }
    else if (i4 < nx + 3*NW) { src = wv; dst = wqkv + 2*NW;   off = i4 - nx - 2*NW; }
    else                     { src = wo; dst = wob;           off = i4 - nx - 3*NW; }
    float4 v = *reinterpret_cast<const float4*>(src + off);
    ushort4 o4; o4.x = f2bf(v.x); o4.y = f2bf(v.y); o4.z = f2bf(v.z); o4.w = f2bf(v.w);
    *reinterpret_cast<ushort4*>(dst + off) = o4;
}

// ---------------- GEMM: C[m][n] = sum_k A[m][k]*B[n][k] ----------------
// 128x128 tile, BK=64, swizzled LDS (chunk ^= row&7, applied via pre-swizzled global src).
// If vt != nullptr, n-blocks with n0 >= 2048 (the V projection) are written TRANSPOSED
// to vt[(b*16+h)*64 + d][s] via a per-wave LDS mini-transpose instead of to C.
template <typename OUT>
__global__ __launch_bounds__(256) void gemm_bt(const u16* __restrict__ A, const u16* __restrict__ B,
                                               OUT* __restrict__ C, int M, int N, int K,
                                               int qcols, float qscale, u16* __restrict__ vt) {
    __shared__ u16 As[128 * 64];
    __shared__ u16 Bs[128 * 64];
    __shared__ u16 Ts[4][16 * 72];   // per-wave transpose scratch
    const int m0 = blockIdx.y * 128, n0 = blockIdx.x * 128;
    const int t = threadIdx.x, w = t >> 6, l = t & 63;
    const int hi = l >> 4;
    const int wr = w >> 1, wc = w & 1;
    f32x4 acc[4][4] = {};

    const int lr = l >> 3;                   // row-within-8
    const int lc = l & 7;                    // 16B chunk
    const int gcol = (lc ^ lr) * 8;          // pre-swizzled source column (elements)
    const u16* Ag = A + (size_t)(m0 + w * 32 + lr) * K + gcol;
    const u16* Bg = B + (size_t)(n0 + w * 32 + lr) * K + gcol;

    for (int k0 = 0; k0 < K; k0 += 64) {
        __syncthreads();
#pragma unroll
        for (int c = 0; c < 4; c++) {
            gll16(Ag + (size_t)c * 8 * K + k0, As + w * 2048 + c * 512);
            gll16(Bg + (size_t)c * 8 * K + k0, Bs + w * 2048 + c * 512);
        }
        __syncthreads();
#pragma unroll
        for (int kk = 0; kk < 2; kk++) {
            bf16x8 af[4], bfr[4];
#pragma unroll
            for (int mi = 0; mi < 4; mi++)
                af[mi] = *(const bf16x8*)&As[(wr * 64 + mi * 16 + (l & 15)) * 64 +
                                             (((kk * 4 + hi) ^ (l & 7)) * 8)];
#pragma unroll
            for (int ni = 0; ni < 4; ni++)
                bfr[ni] = *(const bf16x8*)&Bs[(wc * 64 + ni * 16 + (l & 15)) * 64 +
                                              (((kk * 4 + hi) ^ (l & 7)) * 8)];
#pragma unroll
            for (int mi = 0; mi < 4; mi++)
#pragma unroll
                for (int ni = 0; ni < 4; ni++)
                    acc[mi][ni] = __builtin_amdgcn_mfma_f32_16x16x32_bf16(af[mi], bfr[ni], acc[mi][ni], 0, 0, 0);
        }
    }

    if (vt != nullptr && n0 >= 2048) {
        const int mw = m0 + wr * 64;
        const int bq = mw >> 11;
        const int s0w = mw & (S_LEN - 1);
        const int hd = ((n0 + wc * 64) - 2048) >> 6;
        u16* tb = &Ts[w][0];
#pragma unroll
        for (int ni = 0; ni < 4; ni++) {
#pragma unroll
            for (int mi = 0; mi < 4; mi++) {
                uint2 pk = make_uint2(cvtpk_bf16(acc[mi][ni][0], acc[mi][ni][1]),
                                      cvtpk_bf16(acc[mi][ni][2], acc[mi][ni][3]));
                *(uint2*)&tb[(l & 15) * 72 + mi * 16 + hi * 4] = pk;
            }
            bf16x8 r0 = *(const bf16x8*)&tb[(l & 15) * 72 + hi * 16];
            bf16x8 r1 = *(const bf16x8*)&tb[(l & 15) * 72 + hi * 16 + 8];
            size_t vrow = ((size_t)(bq * 16 + hd) * 64 + ni * 16 + (l & 15)) * S_LEN + s0w + hi * 16;
            *(u16x8*)&vt[vrow]     = (u16x8)r0;
            *(u16x8*)&vt[vrow + 8] = (u16x8)r1;
        }
    } else {
#pragma unroll
        for (int mi = 0; mi < 4; mi++)
#pragma unroll
            for (int ni = 0; ni < 4; ni++)
#pragma unroll
                for (int j = 0; j < 4; j++) {
                    int r = m0 + wr * 64 + mi * 16 + hi * 4 + j;
                    int c = n0 + wc * 64 + ni * 16 + (l & 15);
                    float v = acc[mi][ni][j];
                    if (c < qcols) v *= qscale;
                    if constexpr (__is_same(OUT, u16)) C[(size_t)r * N + c] = f2bf(v);
                    else                               C[(size_t)r * N + c] = v;
                }
    }
}

// ---------------- causal flash attention: dual-q, KVBLK=128 dbuf ----------------
// grid (64 bh, 16 y), p = (y&1) ? 15-(y>>1) : y>>1 (long/short sweeps interleaved in
// dispatch order -> balanced per-CU residency). Block = 256 thr / 4 waves over a 128-row
// q-tile; each wave owns halves A (q128+w*16+q) and B (+64). Per barrier epoch: stage
// 128 kv rows (8 gll16, ~900cy latency) while computing two 64-row sub-tiles (~900cy)
// from the other buffer -> staging latency hidden, barriers halved vs KVBLK=64.
// K staged [128 kv][64 dk] (chunk^=row&7); V staged transposed [64 d][128 kv]
// (16B-chunk ^= d&7 within 8-chunk halves). Static-max softmax P = exp2(s-8);
// straight-line (masked tiles contribute 0) - no conditional live ranges (r9 lesson).
__global__ __launch_bounds__(256, 2) void attn(const u16* __restrict__ QKV, const u16* __restrict__ VT,
                                               u16* __restrict__ O) {
    const int bh = blockIdx.x, y = blockIdx.y;
    const int p = (y & 1) ? 15 - (y >> 1) : (y >> 1);
    const int b = bh >> 4, h = bh & 15;
    const int t = threadIdx.x, w = t >> 6, l = t & 63;
    const int q = l & 15, hi = l >> 4, s7 = q & 7;

    __shared__ u16 KS[2][128][64];     // [cur][kv][dk]  32 KB
    __shared__ u16 VS[2][64][128];     // [cur][d][kv]   32 KB
    __shared__ u16 PS[4][16][64];      // per-wave P (reused A then B)  8 KB

    // K staging: 256 thr x 16B = 4KB = 32 kv-rows per round, 4 rounds per tile
    const int srow = t >> 3, sblk = t & 7;
    const int gsK = (sblk ^ (srow & 7)) * 8;
    const u16* Kg0 = QKV + (size_t)(b * S_LEN + srow) * 3072 + 1024 + h * 64 + gsK;
    // V staging: 16 d-rows x 256B per round, 4 rounds; source chunk pre-swizzled
    const int vrow = t >> 4, vchunk = t & 15;
    const int gsV = ((vchunk & 8) | ((vchunk ^ (vrow & 7)) & 7)) * 8;
    const u16* Vg0 = VT + (size_t)(bh * 64 + vrow) * S_LEN + gsV;

    // K fragment byte offsets within a 64-row sub-tile (row q + ni*16, 128B rows)
    const int kA0 = q * 128 + ((hi ^ s7) << 4);            // kk=0; kk=1 is ^64
    const int kA1 = kA0 ^ 64;
    // V fragment chunk offsets (within row (l&15)+di*16, 256B rows): chunk = s*8+kk*4+hi, ^ (d&7)
    const int vo00 = ((0 << 3) | ((0 * 4 + hi) ^ s7)) << 4;
    const int vo01 = ((0 << 3) | ((1 * 4 + hi) ^ s7)) << 4;
    const int vo10 = ((1 << 3) | ((0 * 4 + hi) ^ s7)) << 4;
    const int vo11 = ((1 << 3) | ((1 * 4 + hi) ^ s7)) << 4;

    char* pbase = (char*)&PS[w][0][0];
    const int pw0 = q * 128 + ((((0 * 2) + (hi >> 1)) ^ s7) << 4) + ((hi & 1) << 3);
    const int pw1 = q * 128 + ((((1 * 2) + (hi >> 1)) ^ s7) << 4) + ((hi & 1) << 3);
    const int pw2 = q * 128 + ((((2 * 2) + (hi >> 1)) ^ s7) << 4) + ((hi & 1) << 3);
    const int pw3 = q * 128 + ((((3 * 2) + (hi >> 1)) ^ s7) << 4) + ((hi & 1) << 3);
    const int pr0 = q * 128 + (((0 * 4 + hi) ^ s7) << 4);
    const int pr1 = q * 128 + (((1 * 4 + hi) ^ s7) << 4);

    const int q128 = p * 128;
    const int npair = p + 1;                               // 128-row kv pairs
    const int qgA = q128 + w * 16 + q;                     // half A q-row
    const int qgB = qgA + 64;                              // half B q-row

    bf16x8 qfA[2], qfB[2];
#pragma unroll
    for (int kk = 0; kk < 2; kk++) {
        qfA[kk] = *(const bf16x8*)&QKV[(size_t)(b * S_LEN + qgA) * 3072 + h * 64 + kk * 32 + hi * 8];
        qfB[kk] = *(const bf16x8*)&QKV[(size_t)(b * S_LEN + qgB) * 3072 + h * 64 + kk * 32 + hi * 8];
    }

    f32x4 oaccA[4] = {}, oaccB[4] = {};
    float ssA = 0.f, ssB = 0.f;

    // prologue: stage pair 0 into buffer 0
#pragma unroll
    for (int blk = 0; blk < 4; blk++) {
        gll16(Kg0 + (size_t)(blk * 32) * 3072, (u16*)KS + blk * 2048 + t * 8);
        gll16(Vg0 + (size_t)(blk * 16) * S_LEN, (u16*)VS + blk * 2048 + t * 8);
    }
    __syncthreads();

#pragma unroll 1
    for (int tt = 0; tt < npair; ++tt) {
        const int cur = tt & 1;
        if (tt + 1 < npair) {
            const size_t kadv = (size_t)(tt + 1) * 128;
#pragma unroll
            for (int blk = 0; blk < 4; blk++) {
                gll16(Kg0 + (kadv + blk * 32) * 3072, (u16*)KS + (cur ^ 1) * 8192 + blk * 2048 + t * 8);
                gll16(Vg0 + (size_t)(blk * 16) * S_LEN + kadv, (u16*)VS + (cur ^ 1) * 8192 + blk * 2048 + t * 8);
            }
        }
#pragma unroll
        for (int s = 0; s < 2; s++) {
            const int kv0 = tt * 128 + s * 64;
            const char* kb = (const char*)KS + cur * 16384 + s * 8192;
            const char* va = (const char*)VS + cur * 16384 + (l & 15) * 256;
            const int voK0 = s ? vo10 : vo00;
            const int voK1 = s ? vo11 : vo01;

            // S^T = K · Q^T for both halves; each K fragment read ONCE
            f32x4 saccA[4] = {}, saccB[4] = {};
            __builtin_amdgcn_s_setprio(1);
#pragma unroll
            for (int kk = 0; kk < 2; kk++) {
                const char* ka = kb + (kk ? kA1 : kA0);
#pragma unroll
                for (int ni = 0; ni < 4; ni++) {
                    bf16x8 kf = *(const bf16x8*)(ka + ni * 2048);
                    saccA[ni] = __builtin_amdgcn_mfma_f32_16x16x32_bf16(kf, qfA[kk], saccA[ni], 0, 0, 0);
                    saccB[ni] = __builtin_amdgcn_mfma_f32_16x16x32_bf16(kf, qfB[kk], saccB[ni], 0, 0, 0);
                }
            }
            __builtin_amdgcn_s_setprio(0);

            // softmax half A (mask -> exp2(s-8) -> row-sum accum -> pack -> LDS -> frags)
            bf16x8 pfA0, pfA1, pfB0, pfB1;
            {
                const int r0 = qgA - kv0;
                if (r0 < 63) {
                    const int rth = r0 - hi * 4;
#pragma unroll
                    for (int ni = 0; ni < 4; ni++)
#pragma unroll
                        for (int j = 0; j < 4; j++)
                            if (ni * 16 + j > rth) saccA[ni][j] = -1e30f;
                }
                float pv[4][4];
#pragma unroll
                for (int ni = 0; ni < 4; ni++)
#pragma unroll
                    for (int j = 0; j < 4; j++) pv[ni][j] = fast_exp2(saccA[ni][j] - 8.0f);
                ssA += ((pv[0][0] + pv[0][1]) + (pv[0][2] + pv[0][3]))
                     + ((pv[1][0] + pv[1][1]) + (pv[1][2] + pv[1][3]))
                     + ((pv[2][0] + pv[2][1]) + (pv[2][2] + pv[2][3]))
                     + ((pv[3][0] + pv[3][1]) + (pv[3][2] + pv[3][3]));
                *(uint2*)(pbase + pw0) = make_uint2(cvtpk_bf16(pv[0][0], pv[0][1]), cvtpk_bf16(pv[0][2], pv[0][3]));
                *(uint2*)(pbase + pw1) = make_uint2(cvtpk_bf16(pv[1][0], pv[1][1]), cvtpk_bf16(pv[1][2], pv[1][3]));
                *(uint2*)(pbase + pw2) = make_uint2(cvtpk_bf16(pv[2][0], pv[2][1]), cvtpk_bf16(pv[2][2], pv[2][3]));
                *(uint2*)(pbase + pw3) = make_uint2(cvtpk_bf16(pv[3][0], pv[3][1]), cvtpk_bf16(pv[3][2], pv[3][3]));
                pfA0 = *(const bf16x8*)(pbase + pr0);
                pfA1 = *(const bf16x8*)(pbase + pr1);
            }
            // softmax half B (reuses the same per-wave P buffer after A's reads)
            {
                const int r0 = qgB - kv0;
                if (r0 < 63) {
                    const int rth = r0 - hi * 4;
#pragma unroll
                    for (int ni = 0; ni < 4; ni++)
#pragma unroll
                        for (int j = 0; j < 4; j++)
                            if (ni * 16 + j > rth) saccB[ni][j] = -1e30f;
                }
                float pv[4][4];
#pragma unroll
                for (int ni = 0; ni < 4; ni++)
#pragma unroll
                    for (int j = 0; j < 4; j++) pv[ni][j] = fast_exp2(saccB[ni][j] - 8.0f);
                ssB += ((pv[0][0] + pv[0][1]) + (pv[0][2] + pv[0][3]))
                     + ((pv[1][0] + pv[1][1]) + (pv[1][2] + pv[1][3]))
                     + ((pv[2][0] + pv[2][1]) + (pv[2][2] + pv[2][3]))
                     + ((pv[3][0] + pv[3][1]) + (pv[3][2] + pv[3][3]));
                *(uint2*)(pbase + pw0) = make_uint2(cvtpk_bf16(pv[0][0], pv[0][1]), cvtpk_bf16(pv[0][2], pv[0][3]));
                *(uint2*)(pbase + pw1) = make_uint2(cvtpk_bf16(pv[1][0], pv[1][1]), cvtpk_bf16(pv[1][2], pv[1][3]));
                *(uint2*)(pbase + pw2) = make_uint2(cvtpk_bf16(pv[2][0], pv[2][1]), cvtpk_bf16(pv[2][2], pv[2][3]));
                *(uint2*)(pbase + pw3) = make_uint2(cvtpk_bf16(pv[3][0], pv[3][1]), cvtpk_bf16(pv[3][2], pv[3][3]));
                pfB0 = *(const bf16x8*)(pbase + pr0);
                pfB1 = *(const bf16x8*)(pbase + pr1);
            }

            // O^T += V^T · P^T for both halves; each V fragment read ONCE
            __builtin_amdgcn_s_setprio(1);
#pragma unroll
            for (int kk = 0; kk < 2; kk++) {
                const int vo = kk ? voK1 : voK0;
                bf16x8 pfa = kk ? pfA1 : pfA0;
                bf16x8 pfb = kk ? pfB1 : pfB0;
#pragma unroll
                for (int di = 0; di < 4; di++) {
                    bf16x8 vf = *(const bf16x8*)(va + vo + di * 4096);
                    oaccA[di] = __builtin_amdgcn_mfma_f32_16x16x32_bf16(vf, pfa, oaccA[di], 0, 0, 0);
                    oaccB[di] = __builtin_amdgcn_mfma_f32_16x16x32_bf16(vf, pfb, oaccB[di], 0, 0, 0);
                }
            }
            __builtin_amdgcn_s_setprio(0);
        }
        __syncthreads();
    }

    // epilogue: normalize and store both halves
    {
        float ssr = ssA;
        ssr += __shfl_xor(ssr, 16, 64);
        ssr += __shfl_xor(ssr, 32, 64);
        float inv = 1.0f / ssr;
#pragma unroll
        for (int di = 0; di < 4; di++) {
            ushort4 o4;
            o4.x = f2bf(oaccA[di][0] * inv);
            o4.y = f2bf(oaccA[di][1] * inv);
            o4.z = f2bf(oaccA[di][2] * inv);
            o4.w = f2bf(oaccA[di][3] * inv);
            *(ushort4*)&O[(size_t)(b * S_LEN + qgA) * DMODEL + h * 64 + di * 16 + hi * 4] = o4;
        }
    }
    {
        float ssr = ssB;
        ssr += __shfl_xor(ssr, 16, 64);
        ssr += __shfl_xor(ssr, 32, 64);
        float inv = 1.0f / ssr;
#pragma unroll
        for (int di = 0; di < 4; di++) {
            ushort4 o4;
            o4.x = f2bf(oaccB[di][0] * inv);
            o4.y = f2bf(oaccB[di][1] * inv);
            o4.z = f2bf(oaccB[di][2] * inv);
            o4.w = f2bf(oaccB[di][3] * inv);
            *(ushort4*)&O[(size_t)(b * S_LEN + qgB) * DMODEL + h * 64 + di * 16 + hi * 4] = o4;
        }
    }
}

extern "C" void kernel_launch(void* const* d_in, const int* in_sizes, int n_in,
                              void* d_out, int out_size, void* d_ws, size_t ws_size,
                              hipStream_t stream) {
    const float* x  = (const float*)d_in[0];
    const float* wq = (const float*)d_in[1];
    const float* wk = (const float*)d_in[2];
    const float* wv = (const float*)d_in[3];
    const float* wo = (const float*)d_in[4];
    const int nx = in_sizes[0];              // 8388608 = 4*2048*1024
    const int BS = nx / DMODEL;              // 8192
    const int NW = DMODEL * DMODEL;

    u16* xb   = (u16*)d_ws;                  // [8192][1024]
    u16* wqkv = xb + (size_t)nx;             // [3072][1024]
    u16* wob  = wqkv + (size_t)3 * NW;       // [1024][1024]
    u16* qkv  = wob + (size_t)NW;            // [8192][3072] (V region unused)
    u16* vt   = qkv + (size_t)BS * 3072;     // [B*H*64][2048]
    u16* ob   = vt + (size_t)nx;             // [8192][1024]

    int ncast = (nx + 4 * NW) / 4 / 256;
    cast_all<<<ncast, 256, 0, stream>>>(x, wq, wk, wv, wo, xb, wqkv, wob, nx);

    const float QSC = 0.125f * 1.44269504088896f;   // 1/sqrt(dk) * log2(e)
    gemm_bt<u16><<<dim3(3072 / 128, BS / 128), 256, 0, stream>>>(xb, wqkv, qkv, BS, 3072, DMODEL,
                                                                 DMODEL, QSC, vt);

    attn<<<dim3((BS / S_LEN) * NH, 16), 256, 0, stream>>>(qkv, vt, ob);

    gemm_bt<float><<<dim3(DMODEL / 128, BS / 128), 256, 0, stream>>>(ob, wob, (float*)d_out, BS, DMODEL, DMODEL,
                                                                     0, 1.0f, nullptr);
}

// Round 12
// 158.607 us; speedup vs baseline: 1.0823x; 1.0823x over previous
//
#include <hip/hip_runtime.h>
#include <hip/hip_bf16.h>
#include <stdint.h>

// MHA forward: B=4, S=2048, D=1024, H=16, dk=64. fp32 in/out, bf16 MFMA internally.
// Pipeline: cast -> QKV GEMM (bf16, BK=64 swizzled LDS, V written transposed in epilogue)
//           -> causal flash attention (dual-q per wave, static-max softmax, KVBLK=64,
//              40KB LDS -> 4 blocks/CU) -> out GEMM.

typedef unsigned short u16;
typedef short bf16x8 __attribute__((ext_vector_type(8)));
typedef float f32x4 __attribute__((ext_vector_type(4)));
typedef unsigned short u16x8 __attribute__((ext_vector_type(8)));

#define S_LEN 2048
#define DMODEL 1024
#define NH 16

__device__ __forceinline__ u16 f2bf(float f) {
    unsigned u = __builtin_bit_cast(unsigned, f);
    unsigned r = (u + 0x7fffu + ((u >> 16) & 1u)) >> 16;
    return (u16)r;
}

__device__ __forceinline__ float fast_exp2(float x) {
    return __builtin_amdgcn_exp2f(x);
}

__device__ __forceinline__ unsigned cvtpk_bf16(float lo, float hi_) {
    unsigned r;
    asm("v_cvt_pk_bf16_f32 %0, %1, %2" : "=v"(r) : "v"(lo), "v"(hi_));
    return r;
}

__device__ __forceinline__ void gll16(const void* g, void* s) {
    __builtin_amdgcn_global_load_lds((const __attribute__((address_space(1))) unsigned*)g,
                                     (__attribute__((address_space(3))) unsigned*)s, 16, 0, 0);
}

// ---------------- cast: fp32 -> bf16, concat QKV weights ----------------
__global__ __launch_bounds__(256) void cast_all(
    const float* __restrict__ x, const float* __restrict__ wq, const float* __restrict__ wk,
    const float* __restrict__ wv, const float* __restrict__ wo,
    u16* __restrict__ xb, u16* __restrict__ wqkv, u16* __restrict__ wob, int nx) {
    const int NW = DMODEL * DMODEL;
    int i4 = (blockIdx.x * 256 + threadIdx.x) * 4;
    const float* src; u16* dst; int off;
    if (i4 < nx)             { src = x;  dst = xb;            off = i4; }
    else if (i4 < nx + NW)   { src = wq; dst = wqkv;          off = i4 - nx; }
    else if (i4 < nx + 2*NW) { src = wk; dst = wqkv + NW;     off = i4 - nx - NW; }
    else if (i4 < nx + 3*NW) { src = wv; dst = wqkv + 2*NW;   off = i4 - nx - 2*NW; }
    else                     { src = wo; dst = wob;           off = i4 - nx - 3*NW; }
    float4 v = *reinterpret_cast<const float4*>(src + off);
    ushort4 o4; o4.x = f2bf(v.x); o4.y = f2bf(v.y); o4.z = f2bf(v.z); o4.w = f2bf(v.w);
    *reinterpret_cast<ushort4*>(dst + off) = o4;
}

// ---------------- GEMM: C[m][n] = sum_k A[m][k]*B[n][k] ----------------
// 128x128 tile, BK=64, swizzled LDS (chunk ^= row&7, applied via pre-swizzled global src).
// If vt != nullptr, n-blocks with n0 >= 2048 (the V projection) are written TRANSPOSED
// to vt[(b*16+h)*64 + d][s] via a per-wave LDS mini-transpose instead of to C.
template <typename OUT>
__global__ __launch_bounds__(256) void gemm_bt(const u16* __restrict__ A, const u16* __restrict__ B,
                                               OUT* __restrict__ C, int M, int N, int K,
                                               int qcols, float qscale, u16* __restrict__ vt) {
    __shared__ u16 As[128 * 64];
    __shared__ u16 Bs[128 * 64];
    __shared__ u16 Ts[4][16 * 72];   // per-wave transpose scratch
    const int m0 = blockIdx.y * 128, n0 = blockIdx.x * 128;
    const int t = threadIdx.x, w = t >> 6, l = t & 63;
    const int hi = l >> 4;
    const int wr = w >> 1, wc = w & 1;
    f32x4 acc[4][4] = {};

    const int lr = l >> 3;                   // row-within-8
    const int lc = l & 7;                    // 16B chunk
    const int gcol = (lc ^ lr) * 8;          // pre-swizzled source column (elements)
    const u16* Ag = A + (size_t)(m0 + w * 32 + lr) * K + gcol;
    const u16* Bg = B + (size_t)(n0 + w * 32 + lr) * K + gcol;

    for (int k0 = 0; k0 < K; k0 += 64) {
        __syncthreads();
#pragma unroll
        for (int c = 0; c < 4; c++) {
            gll16(Ag + (size_t)c * 8 * K + k0, As + w * 2048 + c * 512);
            gll16(Bg + (size_t)c * 8 * K + k0, Bs + w * 2048 + c * 512);
        }
        __syncthreads();
#pragma unroll
        for (int kk = 0; kk < 2; kk++) {
            bf16x8 af[4], bfr[4];
#pragma unroll
            for (int mi = 0; mi < 4; mi++)
                af[mi] = *(const bf16x8*)&As[(wr * 64 + mi * 16 + (l & 15)) * 64 +
                                             (((kk * 4 + hi) ^ (l & 7)) * 8)];
#pragma unroll
            for (int ni = 0; ni < 4; ni++)
                bfr[ni] = *(const bf16x8*)&Bs[(wc * 64 + ni * 16 + (l & 15)) * 64 +
                                              (((kk * 4 + hi) ^ (l & 7)) * 8)];
#pragma unroll
            for (int mi = 0; mi < 4; mi++)
#pragma unroll
                for (int ni = 0; ni < 4; ni++)
                    acc[mi][ni] = __builtin_amdgcn_mfma_f32_16x16x32_bf16(af[mi], bfr[ni], acc[mi][ni], 0, 0, 0);
        }
    }

    if (vt != nullptr && n0 >= 2048) {
        const int mw = m0 + wr * 64;
        const int bq = mw >> 11;
        const int s0w = mw & (S_LEN - 1);
        const int hd = ((n0 + wc * 64) - 2048) >> 6;
        u16* tb = &Ts[w][0];
#pragma unroll
        for (int ni = 0; ni < 4; ni++) {
#pragma unroll
            for (int mi = 0; mi < 4; mi++) {
                uint2 pk = make_uint2(cvtpk_bf16(acc[mi][ni][0], acc[mi][ni][1]),
                                      cvtpk_bf16(acc[mi][ni][2], acc[mi][ni][3]));
                *(uint2*)&tb[(l & 15) * 72 + mi * 16 + hi * 4] = pk;
            }
            bf16x8 r0 = *(const bf16x8*)&tb[(l & 15) * 72 + hi * 16];
            bf16x8 r1 = *(const bf16x8*)&tb[(l & 15) * 72 + hi * 16 + 8];
            size_t vrow = ((size_t)(bq * 16 + hd) * 64 + ni * 16 + (l & 15)) * S_LEN + s0w + hi * 16;
            *(u16x8*)&vt[vrow]     = (u16x8)r0;
            *(u16x8*)&vt[vrow + 8] = (u16x8)r1;
        }
    } else {
#pragma unroll
        for (int mi = 0; mi < 4; mi++)
#pragma unroll
            for (int ni = 0; ni < 4; ni++)
#pragma unroll
                for (int j = 0; j < 4; j++) {
                    int r = m0 + wr * 64 + mi * 16 + hi * 4 + j;
                    int c = n0 + wc * 64 + ni * 16 + (l & 15);
                    float v = acc[mi][ni][j];
                    if (c < qcols) v *= qscale;
                    if constexpr (__is_same(OUT, u16)) C[(size_t)r * N + c] = f2bf(v);
                    else                               C[(size_t)r * N + c] = v;
                }
    }
}

// ---------------- causal flash attention: dual-q per wave, 40KB LDS ----------------
// grid (64 bh, 16 y), p = (y<8) ? y : 23-y  (each CU's 4-block residency set sums to
// exactly 68 kv-iters). Block = 256 thr / 4 waves over a 128-row q-tile; each wave owns
// halves A (q128+w*16+q) and B (+64). Per kv-tile each K/V fragment is ds_read ONCE and
// feeds both halves' MFMAs. Single per-wave P buffer reused A-then-B (in-wave LDS
// ordering) -> 40KB LDS -> 4 blocks/CU. Straight-line body (r9 spill lesson).
// Static-max softmax P = exp2(s-8); swapped operands keep rows lane-local.
__global__ __launch_bounds__(256, 2) void attn(const u16* __restrict__ QKV, const u16* __restrict__ VT,
                                               u16* __restrict__ O) {
    const int bh = blockIdx.x, y = blockIdx.y;
    const int p = (y < 8) ? y : 23 - y;
    const int b = bh >> 4, h = bh & 15;
    const int t = threadIdx.x, w = t >> 6, l = t & 63;
    const int q = l & 15, hi = l >> 4, s7 = q & 7;

    __shared__ u16 SM[2][2][64][64];    // [cur][K/V][row][col]  32 KB
    __shared__ u16 PS[4][16][64];       // per-wave P (reused A then B)  8 KB

    // staging: 256 thr x 16B = 4KB; two pointers cover a 64x64 tile (rows 0-31, 32-63)
    const int srow = t >> 3, sblk = t & 7;
    const int gs = (sblk ^ (srow & 7)) * 8;                // pre-swizzled global source
    const u16* Kg = QKV + (size_t)(b * S_LEN + srow) * 3072 + 1024 + h * 64 + gs;
    const u16* Vg = VT + (size_t)(bh * 64 + srow) * S_LEN + gs;
    const u16* Kg2 = Kg + (size_t)32 * 3072;               // rows +32 (row&7 unchanged)
    const u16* Vg2 = Vg + (size_t)32 * S_LEN;

    const int kA0 = q * 128 + ((hi ^ s7) << 4);            // kk=0; kk=1 is ^64
    const int kA1 = kA0 ^ 64;
    const char* smbase = (const char*)&SM[0][0][0][0];

    char* pbase = (char*)&PS[w][0][0];
    const int pw0 = q * 128 + ((((0 * 2) + (hi >> 1)) ^ s7) << 4) + ((hi & 1) << 3);
    const int pw1 = q * 128 + ((((1 * 2) + (hi >> 1)) ^ s7) << 4) + ((hi & 1) << 3);
    const int pw2 = q * 128 + ((((2 * 2) + (hi >> 1)) ^ s7) << 4) + ((hi & 1) << 3);
    const int pw3 = q * 128 + ((((3 * 2) + (hi >> 1)) ^ s7) << 4) + ((hi & 1) << 3);
    const int pr0 = q * 128 + (((0 * 4 + hi) ^ s7) << 4);
    const int pr1 = q * 128 + (((1 * 4 + hi) ^ s7) << 4);

    const int q128 = p * 128;
    const int nt = 2 * p + 2;
    const int qgA = q128 + w * 16 + q;                     // half A q-row
    const int qgB = qgA + 64;                              // half B q-row

    bf16x8 qfA[2], qfB[2];
#pragma unroll
    for (int kk = 0; kk < 2; kk++) {
        qfA[kk] = *(const bf16x8*)&QKV[(size_t)(b * S_LEN + qgA) * 3072 + h * 64 + kk * 32 + hi * 8];
        qfB[kk] = *(const bf16x8*)&QKV[(size_t)(b * S_LEN + qgB) * 3072 + h * 64 + kk * 32 + hi * 8];
    }

    f32x4 oaccA[4] = {}, oaccB[4] = {};
    float ssA = 0.f, ssB = 0.f;

    gll16(Kg,  (u16*)&SM[0][0][0][0] + t * 8);
    gll16(Kg2, (u16*)&SM[0][0][0][0] + 2048 + t * 8);
    gll16(Vg,  (u16*)&SM[0][1][0][0] + t * 8);
    gll16(Vg2, (u16*)&SM[0][1][0][0] + 2048 + t * 8);
    __syncthreads();

    const u16* KgT  = Kg  + (size_t)64 * 3072;
    const u16* Kg2T = Kg2 + (size_t)64 * 3072;
    const u16* VgT  = Vg  + 64;
    const u16* Vg2T = Vg2 + 64;

#pragma unroll 1
    for (int tt = 0; tt < nt; ++tt) {
        const int cur = tt & 1;
        if (tt + 1 < nt) {
            gll16(KgT,  (u16*)&SM[cur ^ 1][0][0][0] + t * 8);
            gll16(Kg2T, (u16*)&SM[cur ^ 1][0][0][0] + 2048 + t * 8);
            gll16(VgT,  (u16*)&SM[cur ^ 1][1][0][0] + t * 8);
            gll16(Vg2T, (u16*)&SM[cur ^ 1][1][0][0] + 2048 + t * 8);
            KgT  += (size_t)64 * 3072;
            Kg2T += (size_t)64 * 3072;
            VgT  += 64;
            Vg2T += 64;
        }
        const int kv0 = tt * 64;
        const char* kb = smbase + cur * 16384;

        // S^T = K · Q^T for both halves; each K fragment read ONCE
        f32x4 saccA[4] = {}, saccB[4] = {};
        __builtin_amdgcn_s_setprio(1);
#pragma unroll
        for (int kk = 0; kk < 2; kk++) {
            const char* ka = kb + (kk ? kA1 : kA0);
#pragma unroll
            for (int ni = 0; ni < 4; ni++) {
                bf16x8 kf = *(const bf16x8*)(ka + ni * 2048);
                saccA[ni] = __builtin_amdgcn_mfma_f32_16x16x32_bf16(kf, qfA[kk], saccA[ni], 0, 0, 0);
                saccB[ni] = __builtin_amdgcn_mfma_f32_16x16x32_bf16(kf, qfB[kk], saccB[ni], 0, 0, 0);
            }
        }
        __builtin_amdgcn_s_setprio(0);

        // softmax half A (mask -> exp2(s-8) -> row-sum accum -> pack -> LDS -> frags)
        bf16x8 pfA0, pfA1, pfB0, pfB1;
        {
            const int r0 = qgA - kv0;
            if (r0 < 63) {
                const int rth = r0 - hi * 4;
#pragma unroll
                for (int ni = 0; ni < 4; ni++)
#pragma unroll
                    for (int j = 0; j < 4; j++)
                        if (ni * 16 + j > rth) saccA[ni][j] = -1e30f;
            }
            float pv[4][4];
#pragma unroll
            for (int ni = 0; ni < 4; ni++)
#pragma unroll
                for (int j = 0; j < 4; j++) pv[ni][j] = fast_exp2(saccA[ni][j] - 8.0f);
            ssA += ((pv[0][0] + pv[0][1]) + (pv[0][2] + pv[0][3]))
                 + ((pv[1][0] + pv[1][1]) + (pv[1][2] + pv[1][3]))
                 + ((pv[2][0] + pv[2][1]) + (pv[2][2] + pv[2][3]))
                 + ((pv[3][0] + pv[3][1]) + (pv[3][2] + pv[3][3]));
            *(uint2*)(pbase + pw0) = make_uint2(cvtpk_bf16(pv[0][0], pv[0][1]), cvtpk_bf16(pv[0][2], pv[0][3]));
            *(uint2*)(pbase + pw1) = make_uint2(cvtpk_bf16(pv[1][0], pv[1][1]), cvtpk_bf16(pv[1][2], pv[1][3]));
            *(uint2*)(pbase + pw2) = make_uint2(cvtpk_bf16(pv[2][0], pv[2][1]), cvtpk_bf16(pv[2][2], pv[2][3]));
            *(uint2*)(pbase + pw3) = make_uint2(cvtpk_bf16(pv[3][0], pv[3][1]), cvtpk_bf16(pv[3][2], pv[3][3]));
            pfA0 = *(const bf16x8*)(pbase + pr0);
            pfA1 = *(const bf16x8*)(pbase + pr1);
        }
        // softmax half B (reuses the same per-wave P buffer after A's reads)
        {
            const int r0 = qgB - kv0;
            if (r0 < 63) {
                const int rth = r0 - hi * 4;
#pragma unroll
                for (int ni = 0; ni < 4; ni++)
#pragma unroll
                    for (int j = 0; j < 4; j++)
                        if (ni * 16 + j > rth) saccB[ni][j] = -1e30f;
            }
            float pv[4][4];
#pragma unroll
            for (int ni = 0; ni < 4; ni++)
#pragma unroll
                for (int j = 0; j < 4; j++) pv[ni][j] = fast_exp2(saccB[ni][j] - 8.0f);
            ssB += ((pv[0][0] + pv[0][1]) + (pv[0][2] + pv[0][3]))
                 + ((pv[1][0] + pv[1][1]) + (pv[1][2] + pv[1][3]))
                 + ((pv[2][0] + pv[2][1]) + (pv[2][2] + pv[2][3]))
                 + ((pv[3][0] + pv[3][1]) + (pv[3][2] + pv[3][3]));
            *(uint2*)(pbase + pw0) = make_uint2(cvtpk_bf16(pv[0][0], pv[0][1]), cvtpk_bf16(pv[0][2], pv[0][3]));
            *(uint2*)(pbase + pw1) = make_uint2(cvtpk_bf16(pv[1][0], pv[1][1]), cvtpk_bf16(pv[1][2], pv[1][3]));
            *(uint2*)(pbase + pw2) = make_uint2(cvtpk_bf16(pv[2][0], pv[2][1]), cvtpk_bf16(pv[2][2], pv[2][3]));
            *(uint2*)(pbase + pw3) = make_uint2(cvtpk_bf16(pv[3][0], pv[3][1]), cvtpk_bf16(pv[3][2], pv[3][3]));
            pfB0 = *(const bf16x8*)(pbase + pr0);
            pfB1 = *(const bf16x8*)(pbase + pr1);
        }

        // O^T += V^T · P^T for both halves; each V fragment read ONCE
        const char* vb = kb + 8192;
        __builtin_amdgcn_s_setprio(1);
#pragma unroll
        for (int kk = 0; kk < 2; kk++) {
            const char* va = vb + (kk ? kA1 : kA0);
            bf16x8 pfa = kk ? pfA1 : pfA0;
            bf16x8 pfb = kk ? pfB1 : pfB0;
#pragma unroll
            for (int di = 0; di < 4; di++) {
                bf16x8 vf = *(const bf16x8*)(va + di * 2048);
                oaccA[di] = __builtin_amdgcn_mfma_f32_16x16x32_bf16(vf, pfa, oaccA[di], 0, 0, 0);
                oaccB[di] = __builtin_amdgcn_mfma_f32_16x16x32_bf16(vf, pfb, oaccB[di], 0, 0, 0);
            }
        }
        __builtin_amdgcn_s_setprio(0);
        __syncthreads();
    }

    // epilogue: normalize and store both halves
    {
        float ssr = ssA;
        ssr += __shfl_xor(ssr, 16, 64);
        ssr += __shfl_xor(ssr, 32, 64);
        float inv = 1.0f / ssr;
#pragma unroll
        for (int di = 0; di < 4; di++) {
            ushort4 o4;
            o4.x = f2bf(oaccA[di][0] * inv);
            o4.y = f2bf(oaccA[di][1] * inv);
            o4.z = f2bf(oaccA[di][2] * inv);
            o4.w = f2bf(oaccA[di][3] * inv);
            *(ushort4*)&O[(size_t)(b * S_LEN + qgA) * DMODEL + h * 64 + di * 16 + hi * 4] = o4;
        }
    }
    {
        float ssr = ssB;
        ssr += __shfl_xor(ssr, 16, 64);
        ssr += __shfl_xor(ssr, 32, 64);
        float inv = 1.0f / ssr;
#pragma unroll
        for (int di = 0; di < 4; di++) {
            ushort4 o4;
            o4.x = f2bf(oaccB[di][0] * inv);
            o4.y = f2bf(oaccB[di][1] * inv);
            o4.z = f2bf(oaccB[di][2] * inv);
            o4.w = f2bf(oaccB[di][3] * inv);
            *(ushort4*)&O[(size_t)(b * S_LEN + qgB) * DMODEL + h * 64 + di * 16 + hi * 4] = o4;
        }
    }
}

extern "C" void kernel_launch(void* const* d_in, const int* in_sizes, int n_in,
                              void* d_out, int out_size, void* d_ws, size_t ws_size,
                              hipStream_t stream) {
    const float* x  = (const float*)d_in[0];
    const float* wq = (const float*)d_in[1];
    const float* wk = (const float*)d_in[2];
    const float* wv = (const float*)d_in[3];
    const float* wo = (const float*)d_in[4];
    const int nx = in_sizes[0];              // 8388608 = 4*2048*1024
    const int BS = nx / DMODEL;              // 8192
    const int NW = DMODEL * DMODEL;

    u16* xb   = (u16*)d_ws;                  // [8192][1024]
    u16* wqkv = xb + (size_t)nx;             // [3072][1024]
    u16* wob  = wqkv + (size_t)3 * NW;       // [1024][1024]
    u16* qkv  = wob + (size_t)NW;            // [8192][3072] (V region unused)
    u16* vt   = qkv + (size_t)BS * 3072;     // [B*H*64][2048]
    u16* ob   = vt + (size_t)nx;             // [8192][1024]

    int ncast = (nx + 4 * NW) / 4 / 256;
    cast_all<<<ncast, 256, 0, stream>>>(x, wq, wk, wv, wo, xb, wqkv, wob, nx);

    const float QSC = 0.125f * 1.44269504088896f;   // 1/sqrt(dk) * log2(e)
    gemm_bt<u16><<<dim3(3072 / 128, BS / 128), 256, 0, stream>>>(xb, wqkv, qkv, BS, 3072, DMODEL,
                                                                 DMODEL, QSC, vt);

    attn<<<dim3((BS / S_LEN) * NH, 16), 256, 0, stream>>>(qkv, vt, ob);

    gemm_bt<float><<<dim3(DMODEL / 128, BS / 128), 256, 0, stream>>>(ob, wob, (float*)d_out, BS, DMODEL, DMODEL,
                                                                     0, 1.0f, nullptr);
}

// Round 13
// 153.715 us; speedup vs baseline: 1.1167x; 1.0318x over previous
//
#include <hip/hip_runtime.h>
#include <hip/hip_bf16.h>
#include <stdint.h>

// MHA forward: B=4, S=2048, D=1024, H=16, dk=64. fp32 in/out, bf16 MFMA internally.
// Pipeline: cast -> QKV GEMM (bf16, BK=64 swizzled LDS, V written transposed in epilogue)
//           -> causal flash attention (dual-q per wave, static-max softmax, in-register
//              P transpose via permlane16/32_swap - no P LDS roundtrip) -> out GEMM.

typedef unsigned short u16;
typedef short bf16x8 __attribute__((ext_vector_type(8)));
typedef float f32x4 __attribute__((ext_vector_type(4)));
typedef unsigned short u16x8 __attribute__((ext_vector_type(8)));
typedef unsigned int u32x4 __attribute__((ext_vector_type(4)));

#define S_LEN 2048
#define DMODEL 1024
#define NH 16

__device__ __forceinline__ u16 f2bf(float f) {
    unsigned u = __builtin_bit_cast(unsigned, f);
    unsigned r = (u + 0x7fffu + ((u >> 16) & 1u)) >> 16;
    return (u16)r;
}

__device__ __forceinline__ float fast_exp2(float x) {
    return __builtin_amdgcn_exp2f(x);
}

__device__ __forceinline__ unsigned cvtpk_bf16(float lo, float hi_) {
    unsigned r;
    asm("v_cvt_pk_bf16_f32 %0, %1, %2" : "=v"(r) : "v"(lo), "v"(hi_));
    return r;
}

// v_permlane32_swap_b32: vdst lanes 32-63 <-> vsrc lanes 0-31 (both regs rewritten)
__device__ __forceinline__ void pl32swap(unsigned& a, unsigned& b) {
    asm("v_permlane32_swap_b32 %0, %1" : "+v"(a), "+v"(b));
}
// v_permlane16_swap_b32: vdst odd 16-lane rows <-> vsrc even rows
__device__ __forceinline__ void pl16swap(unsigned& a, unsigned& b) {
    asm("v_permlane16_swap_b32 %0, %1" : "+v"(a), "+v"(b));
}

__device__ __forceinline__ void gll16(const void* g, void* s) {
    __builtin_amdgcn_global_load_lds((const __attribute__((address_space(1))) unsigned*)g,
                                     (__attribute__((address_space(3))) unsigned*)s, 16, 0, 0);
}

// ---------------- cast: fp32 -> bf16, concat QKV weights ----------------
__global__ __launch_bounds__(256) void cast_all(
    const float* __restrict__ x, const float* __restrict__ wq, const float* __restrict__ wk,
    const float* __restrict__ wv, const float* __restrict__ wo,
    u16* __restrict__ xb, u16* __restrict__ wqkv, u16* __restrict__ wob, int nx) {
    const int NW = DMODEL * DMODEL;
    int i4 = (blockIdx.x * 256 + threadIdx.x) * 4;
    const float* src; u16* dst; int off;
    if (i4 < nx)             { src = x;  dst = xb;            off = i4; }
    else if (i4 < nx + NW)   { src = wq; dst = wqkv;          off = i4 - nx; }
    else if (i4 < nx + 2*NW) { src = wk; dst = wqkv + NW;     off = i4 - nx - NW; }
    else if (i4 < nx + 3*NW) { src = wv; dst = wqkv + 2*NW;   off = i4 - nx - 2*NW; }
    else                     { src = wo; dst = wob;           off = i4 - nx - 3*NW; }
    float4 v = *reinterpret_cast<const float4*>(src + off);
    ushort4 o4; o4.x = f2bf(v.x); o4.y = f2bf(v.y); o4.z = f2bf(v.z); o4.w = f2bf(v.w);
    *reinterpret_cast<ushort4*>(dst + off) = o4;
}

// ---------------- GEMM: C[m][n] = sum_k A[m][k]*B[n][k] ----------------
// 128x128 tile, BK=64, swizzled LDS (chunk ^= row&7, applied via pre-swizzled global src).
// If vt != nullptr, n-blocks with n0 >= 2048 (the V projection) are written TRANSPOSED
// to vt[(b*16+h)*64 + d][s] via a per-wave LDS mini-transpose instead of to C.
template <typename OUT>
__global__ __launch_bounds__(256) void gemm_bt(const u16* __restrict__ A, const u16* __restrict__ B,
                                               OUT* __restrict__ C, int M, int N, int K,
                                               int qcols, float qscale, u16* __restrict__ vt) {
    __shared__ u16 As[128 * 64];
    __shared__ u16 Bs[128 * 64];
    __shared__ u16 Ts[4][16 * 72];   // per-wave transpose scratch
    const int m0 = blockIdx.y * 128, n0 = blockIdx.x * 128;
    const int t = threadIdx.x, w = t >> 6, l = t & 63;
    const int hi = l >> 4;
    const int wr = w >> 1, wc = w & 1;
    f32x4 acc[4][4] = {};

    const int lr = l >> 3;                   // row-within-8
    const int lc = l & 7;                    // 16B chunk
    const int gcol = (lc ^ lr) * 8;          // pre-swizzled source column (elements)
    const u16* Ag = A + (size_t)(m0 + w * 32 + lr) * K + gcol;
    const u16* Bg = B + (size_t)(n0 + w * 32 + lr) * K + gcol;

    for (int k0 = 0; k0 < K; k0 += 64) {
        __syncthreads();
#pragma unroll
        for (int c = 0; c < 4; c++) {
            gll16(Ag + (size_t)c * 8 * K + k0, As + w * 2048 + c * 512);
            gll16(Bg + (size_t)c * 8 * K + k0, Bs + w * 2048 + c * 512);
        }
        __syncthreads();
#pragma unroll
        for (int kk = 0; kk < 2; kk++) {
            bf16x8 af[4], bfr[4];
#pragma unroll
            for (int mi = 0; mi < 4; mi++)
                af[mi] = *(const bf16x8*)&As[(wr * 64 + mi * 16 + (l & 15)) * 64 +
                                             (((kk * 4 + hi) ^ (l & 7)) * 8)];
#pragma unroll
            for (int ni = 0; ni < 4; ni++)
                bfr[ni] = *(const bf16x8*)&Bs[(wc * 64 + ni * 16 + (l & 15)) * 64 +
                                              (((kk * 4 + hi) ^ (l & 7)) * 8)];
#pragma unroll
            for (int mi = 0; mi < 4; mi++)
#pragma unroll
                for (int ni = 0; ni < 4; ni++)
                    acc[mi][ni] = __builtin_amdgcn_mfma_f32_16x16x32_bf16(af[mi], bfr[ni], acc[mi][ni], 0, 0, 0);
        }
    }

    if (vt != nullptr && n0 >= 2048) {
        const int mw = m0 + wr * 64;
        const int bq = mw >> 11;
        const int s0w = mw & (S_LEN - 1);
        const int hd = ((n0 + wc * 64) - 2048) >> 6;
        u16* tb = &Ts[w][0];
#pragma unroll
        for (int ni = 0; ni < 4; ni++) {
#pragma unroll
            for (int mi = 0; mi < 4; mi++) {
                uint2 pk = make_uint2(cvtpk_bf16(acc[mi][ni][0], acc[mi][ni][1]),
                                      cvtpk_bf16(acc[mi][ni][2], acc[mi][ni][3]));
                *(uint2*)&tb[(l & 15) * 72 + mi * 16 + hi * 4] = pk;
            }
            bf16x8 r0 = *(const bf16x8*)&tb[(l & 15) * 72 + hi * 16];
            bf16x8 r1 = *(const bf16x8*)&tb[(l & 15) * 72 + hi * 16 + 8];
            size_t vrow = ((size_t)(bq * 16 + hd) * 64 + ni * 16 + (l & 15)) * S_LEN + s0w + hi * 16;
            *(u16x8*)&vt[vrow]     = (u16x8)r0;
            *(u16x8*)&vt[vrow + 8] = (u16x8)r1;
        }
    } else {
#pragma unroll
        for (int mi = 0; mi < 4; mi++)
#pragma unroll
            for (int ni = 0; ni < 4; ni++)
#pragma unroll
                for (int j = 0; j < 4; j++) {
                    int r = m0 + wr * 64 + mi * 16 + hi * 4 + j;
                    int c = n0 + wc * 64 + ni * 16 + (l & 15);
                    float v = acc[mi][ni][j];
                    if (c < qcols) v *= qscale;
                    if constexpr (__is_same(OUT, u16)) C[(size_t)r * N + c] = f2bf(v);
                    else                               C[(size_t)r * N + c] = v;
                }
    }
}

// ---------------- causal flash attention: dual-q, in-register P transpose ----------------
// grid (64 bh, 16 y), p = (y<8) ? y : 23-y. Block = 256 thr / 4 waves over a 128-row
// q-tile; each wave owns halves A (q128+w*16+q) and B (+64); K/V fragments read ONCE
// per wave-iter serve both halves. Static-max softmax P = exp2(s-8).
// P redistribution (lane(q,hi) holds keys 16ni+4hi+j; PV A-frag needs keys 8hi..8hi+7)
// done IN-REGISTER: cvt_pk pairs then permlane32_swap+permlane16_swap per dword pair
// ((c[n],c[n+1]) -> (t, t+2)); no P LDS roundtrip, PS buffer deleted (LDS 32KB).
__global__ __launch_bounds__(256, 2) void attn(const u16* __restrict__ QKV, const u16* __restrict__ VT,
                                               u16* __restrict__ O) {
    const int bh = blockIdx.x, y = blockIdx.y;
    const int p = (y < 8) ? y : 23 - y;
    const int b = bh >> 4, h = bh & 15;
    const int t = threadIdx.x, w = t >> 6, l = t & 63;
    const int q = l & 15, hi = l >> 4, s7 = q & 7;

    __shared__ u16 SM[2][2][64][64];    // [cur][K/V][row][col]  32 KB

    const int srow = t >> 3, sblk = t & 7;
    const int gs = (sblk ^ (srow & 7)) * 8;                // pre-swizzled global source
    const u16* Kg = QKV + (size_t)(b * S_LEN + srow) * 3072 + 1024 + h * 64 + gs;
    const u16* Vg = VT + (size_t)(bh * 64 + srow) * S_LEN + gs;
    const u16* Kg2 = Kg + (size_t)32 * 3072;               // rows +32 (row&7 unchanged)
    const u16* Vg2 = Vg + (size_t)32 * S_LEN;

    const int kA0 = q * 128 + ((hi ^ s7) << 4);            // kk=0; kk=1 is ^64
    const int kA1 = kA0 ^ 64;
    const char* smbase = (const char*)&SM[0][0][0][0];

    const int q128 = p * 128;
    const int nt = 2 * p + 2;
    const int qgA = q128 + w * 16 + q;                     // half A q-row
    const int qgB = qgA + 64;                              // half B q-row

    bf16x8 qfA[2], qfB[2];
#pragma unroll
    for (int kk = 0; kk < 2; kk++) {
        qfA[kk] = *(const bf16x8*)&QKV[(size_t)(b * S_LEN + qgA) * 3072 + h * 64 + kk * 32 + hi * 8];
        qfB[kk] = *(const bf16x8*)&QKV[(size_t)(b * S_LEN + qgB) * 3072 + h * 64 + kk * 32 + hi * 8];
    }

    f32x4 oaccA[4] = {}, oaccB[4] = {};
    float ssA = 0.f, ssB = 0.f;

    gll16(Kg,  (u16*)&SM[0][0][0][0] + t * 8);
    gll16(Kg2, (u16*)&SM[0][0][0][0] + 2048 + t * 8);
    gll16(Vg,  (u16*)&SM[0][1][0][0] + t * 8);
    gll16(Vg2, (u16*)&SM[0][1][0][0] + 2048 + t * 8);
    __syncthreads();

    const u16* KgT  = Kg  + (size_t)64 * 3072;
    const u16* Kg2T = Kg2 + (size_t)64 * 3072;
    const u16* VgT  = Vg  + 64;
    const u16* Vg2T = Vg2 + 64;

#pragma unroll 1
    for (int tt = 0; tt < nt; ++tt) {
        const int cur = tt & 1;
        if (tt + 1 < nt) {
            gll16(KgT,  (u16*)&SM[cur ^ 1][0][0][0] + t * 8);
            gll16(Kg2T, (u16*)&SM[cur ^ 1][0][0][0] + 2048 + t * 8);
            gll16(VgT,  (u16*)&SM[cur ^ 1][1][0][0] + t * 8);
            gll16(Vg2T, (u16*)&SM[cur ^ 1][1][0][0] + 2048 + t * 8);
            KgT  += (size_t)64 * 3072;
            Kg2T += (size_t)64 * 3072;
            VgT  += 64;
            Vg2T += 64;
        }
        const int kv0 = tt * 64;
        const char* kb = smbase + cur * 16384;

        // S^T = K · Q^T for both halves; each K fragment read ONCE
        f32x4 saccA[4] = {}, saccB[4] = {};
        __builtin_amdgcn_s_setprio(1);
#pragma unroll
        for (int kk = 0; kk < 2; kk++) {
            const char* ka = kb + (kk ? kA1 : kA0);
#pragma unroll
            for (int ni = 0; ni < 4; ni++) {
                bf16x8 kf = *(const bf16x8*)(ka + ni * 2048);
                saccA[ni] = __builtin_amdgcn_mfma_f32_16x16x32_bf16(kf, qfA[kk], saccA[ni], 0, 0, 0);
                saccB[ni] = __builtin_amdgcn_mfma_f32_16x16x32_bf16(kf, qfB[kk], saccB[ni], 0, 0, 0);
            }
        }
        __builtin_amdgcn_s_setprio(0);

        // softmax half A: mask -> exp2(s-8) -> row-sum accum -> pack -> permlane transpose
        bf16x8 pfA0, pfA1, pfB0, pfB1;
        {
            const int r0 = qgA - kv0;
            if (r0 < 63) {
                const int rth = r0 - hi * 4;
#pragma unroll
                for (int ni = 0; ni < 4; ni++)
#pragma unroll
                    for (int j = 0; j < 4; j++)
                        if (ni * 16 + j > rth) saccA[ni][j] = -1e30f;
            }
            float pv[4][4];
#pragma unroll
            for (int ni = 0; ni < 4; ni++)
#pragma unroll
                for (int j = 0; j < 4; j++) pv[ni][j] = fast_exp2(saccA[ni][j] - 8.0f);
            ssA += ((pv[0][0] + pv[0][1]) + (pv[0][2] + pv[0][3]))
                 + ((pv[1][0] + pv[1][1]) + (pv[1][2] + pv[1][3]))
                 + ((pv[2][0] + pv[2][1]) + (pv[2][2] + pv[2][3]))
                 + ((pv[3][0] + pv[3][1]) + (pv[3][2] + pv[3][3]));
            unsigned c00 = cvtpk_bf16(pv[0][0], pv[0][1]), c01 = cvtpk_bf16(pv[0][2], pv[0][3]);
            unsigned c10 = cvtpk_bf16(pv[1][0], pv[1][1]), c11 = cvtpk_bf16(pv[1][2], pv[1][3]);
            unsigned c20 = cvtpk_bf16(pv[2][0], pv[2][1]), c21 = cvtpk_bf16(pv[2][2], pv[2][3]);
            unsigned c30 = cvtpk_bf16(pv[3][0], pv[3][1]), c31 = cvtpk_bf16(pv[3][2], pv[3][3]);
            pl32swap(c00, c10); pl16swap(c00, c10);   // c00=t0, c10=t2 (kk=0)
            pl32swap(c01, c11); pl16swap(c01, c11);   // c01=t1, c11=t3
            pl32swap(c20, c30); pl16swap(c20, c30);   // kk=1
            pl32swap(c21, c31); pl16swap(c21, c31);
            u32x4 f0 = {c00, c01, c10, c11};
            u32x4 f1 = {c20, c21, c30, c31};
            pfA0 = __builtin_bit_cast(bf16x8, f0);
            pfA1 = __builtin_bit_cast(bf16x8, f1);
        }
        // softmax half B
        {
            const int r0 = qgB - kv0;
            if (r0 < 63) {
                const int rth = r0 - hi * 4;
#pragma unroll
                for (int ni = 0; ni < 4; ni++)
#pragma unroll
                    for (int j = 0; j < 4; j++)
                        if (ni * 16 + j > rth) saccB[ni][j] = -1e30f;
            }
            float pv[4][4];
#pragma unroll
            for (int ni = 0; ni < 4; ni++)
#pragma unroll
                for (int j = 0; j < 4; j++) pv[ni][j] = fast_exp2(saccB[ni][j] - 8.0f);
            ssB += ((pv[0][0] + pv[0][1]) + (pv[0][2] + pv[0][3]))
                 + ((pv[1][0] + pv[1][1]) + (pv[1][2] + pv[1][3]))
                 + ((pv[2][0] + pv[2][1]) + (pv[2][2] + pv[2][3]))
                 + ((pv[3][0] + pv[3][1]) + (pv[3][2] + pv[3][3]));
            unsigned c00 = cvtpk_bf16(pv[0][0], pv[0][1]), c01 = cvtpk_bf16(pv[0][2], pv[0][3]);
            unsigned c10 = cvtpk_bf16(pv[1][0], pv[1][1]), c11 = cvtpk_bf16(pv[1][2], pv[1][3]);
            unsigned c20 = cvtpk_bf16(pv[2][0], pv[2][1]), c21 = cvtpk_bf16(pv[2][2], pv[2][3]);
            unsigned c30 = cvtpk_bf16(pv[3][0], pv[3][1]), c31 = cvtpk_bf16(pv[3][2], pv[3][3]);
            pl32swap(c00, c10); pl16swap(c00, c10);
            pl32swap(c01, c11); pl16swap(c01, c11);
            pl32swap(c20, c30); pl16swap(c20, c30);
            pl32swap(c21, c31); pl16swap(c21, c31);
            u32x4 f0 = {c00, c01, c10, c11};
            u32x4 f1 = {c20, c21, c30, c31};
            pfB0 = __builtin_bit_cast(bf16x8, f0);
            pfB1 = __builtin_bit_cast(bf16x8, f1);
        }

        // O^T += V^T · P^T for both halves; each V fragment read ONCE
        const char* vb = kb + 8192;
        __builtin_amdgcn_s_setprio(1);
#pragma unroll
        for (int kk = 0; kk < 2; kk++) {
            const char* va = vb + (kk ? kA1 : kA0);
            bf16x8 pfa = kk ? pfA1 : pfA0;
            bf16x8 pfb = kk ? pfB1 : pfB0;
#pragma unroll
            for (int di = 0; di < 4; di++) {
                bf16x8 vf = *(const bf16x8*)(va + di * 2048);
                oaccA[di] = __builtin_amdgcn_mfma_f32_16x16x32_bf16(vf, pfa, oaccA[di], 0, 0, 0);
                oaccB[di] = __builtin_amdgcn_mfma_f32_16x16x32_bf16(vf, pfb, oaccB[di], 0, 0, 0);
            }
        }
        __builtin_amdgcn_s_setprio(0);
        __syncthreads();
    }

    // epilogue: normalize and store both halves
    {
        float ssr = ssA;
        ssr += __shfl_xor(ssr, 16, 64);
        ssr += __shfl_xor(ssr, 32, 64);
        float inv = 1.0f / ssr;
#pragma unroll
        for (int di = 0; di < 4; di++) {
            ushort4 o4;
            o4.x = f2bf(oaccA[di][0] * inv);
            o4.y = f2bf(oaccA[di][1] * inv);
            o4.z = f2bf(oaccA[di][2] * inv);
            o4.w = f2bf(oaccA[di][3] * inv);
            *(ushort4*)&O[(size_t)(b * S_LEN + qgA) * DMODEL + h * 64 + di * 16 + hi * 4] = o4;
        }
    }
    {
        float ssr = ssB;
        ssr += __shfl_xor(ssr, 16, 64);
        ssr += __shfl_xor(ssr, 32, 64);
        float inv = 1.0f / ssr;
#pragma unroll
        for (int di = 0; di < 4; di++) {
            ushort4 o4;
            o4.x = f2bf(oaccB[di][0] * inv);
            o4.y = f2bf(oaccB[di][1] * inv);
            o4.z = f2bf(oaccB[di][2] * inv);
            o4.w = f2bf(oaccB[di][3] * inv);
            *(ushort4*)&O[(size_t)(b * S_LEN + qgB) * DMODEL + h * 64 + di * 16 + hi * 4] = o4;
        }
    }
}

extern "C" void kernel_launch(void* const* d_in, const int* in_sizes, int n_in,
                              void* d_out, int out_size, void* d_ws, size_t ws_size,
                              hipStream_t stream) {
    const float* x  = (const float*)d_in[0];
    const float* wq = (const float*)d_in[1];
    const float* wk = (const float*)d_in[2];
    const float* wv = (const float*)d_in[3];
    const float* wo = (const float*)d_in[4];
    const int nx = in_sizes[0];              // 8388608 = 4*2048*1024
    const int BS = nx / DMODEL;              // 8192
    const int NW = DMODEL * DMODEL;

    u16* xb   = (u16*)d_ws;                  // [8192][1024]
    u16* wqkv = xb + (size_t)nx;             // [3072][1024]
    u16* wob  = wqkv + (size_t)3 * NW;       // [1024][1024]
    u16* qkv  = wob + (size_t)NW;            // [8192][3072] (V region unused)
    u16* vt   = qkv + (size_t)BS * 3072;     // [B*H*64][2048]
    u16* ob   = vt + (size_t)nx;             // [8192][1024]

    int ncast = (nx + 4 * NW) / 4 / 256;
    cast_all<<<ncast, 256, 0, stream>>>(x, wq, wk, wv, wo, xb, wqkv, wob, nx);

    const float QSC = 0.125f * 1.44269504088896f;   // 1/sqrt(dk) * log2(e)
    gemm_bt<u16><<<dim3(3072 / 128, BS / 128), 256, 0, stream>>>(xb, wqkv, qkv, BS, 3072, DMODEL,
                                                                 DMODEL, QSC, vt);

    attn<<<dim3((BS / S_LEN) * NH, 16), 256, 0, stream>>>(qkv, vt, ob);

    gemm_bt<float><<<dim3(DMODEL / 128, BS / 128), 256, 0, stream>>>(ob, wob, (float*)d_out, BS, DMODEL, DMODEL,
                                                                     0, 1.0f, nullptr);
}